// Round 16
// baseline (141.909 us; speedup 1.0000x reference)
//
#include <hip/hip_runtime.h>
#include <hip/hip_bf16.h>

typedef __bf16 bf16x8 __attribute__((ext_vector_type(8)));
typedef __bf16 bf16x4 __attribute__((ext_vector_type(4)));
typedef __bf16 bf16x2 __attribute__((ext_vector_type(2)));
typedef float f32x4 __attribute__((ext_vector_type(4)));
typedef unsigned int u32x2 __attribute__((ext_vector_type(2)));

#define MFMA16(a, b, c) __builtin_amdgcn_mfma_f32_16x16x32_bf16(a, b, c, 0, 0, 0)

static constexpr int M_ = 4096;     // B*S rows

__device__ __forceinline__ void gload_lds16(const void* g, void* l) {
  __builtin_amdgcn_global_load_lds((const __attribute__((address_space(1))) void*)g,
                                   (__attribute__((address_space(3))) void*)l, 16, 0, 0);
}

// single-instruction 2^x (inputs bounded |x|<~12 here; no denorm fixup needed)
__device__ __forceinline__ float exp2_hw(float x) {
  float r;
  asm("v_exp_f32 %0, %1" : "=v"(r) : "v"(x));
  return r;
}

__device__ __forceinline__ bf16x8 cvt8(float4 x, float4 y) {
  bf16x8 o;
  o[0] = (__bf16)x.x; o[1] = (__bf16)x.y; o[2] = (__bf16)x.z; o[3] = (__bf16)x.w;
  o[4] = (__bf16)y.x; o[5] = (__bf16)y.y; o[6] = (__bf16)y.z; o[7] = (__bf16)y.w;
  return o;
}

// swizzled LDS u16 index for 64-col bf16 tiles (128B rows, 8 granules):
// stored granule = logical granule ^ (row & 7)
#define SWZ(rowv, c16) (((rowv) * 64) + (((c16) ^ ((rowv) & 7)) * 8))

// ---------------- fused prep: cvt fc_w, wtrans x3, mask bits ----------------
__global__ __launch_bounds__(256) void prep(const float* __restrict__ fc_w,
                                            const float* __restrict__ wq,
                                            const float* __restrict__ wk,
                                            const float* __restrict__ wv,
                                            const int* __restrict__ mask,
                                            __bf16* __restrict__ WFC,
                                            __bf16* __restrict__ W3T,
                                            unsigned long long* __restrict__ bits) {
  __shared__ float tile[64][65];
  int bx = blockIdx.x;
  const int t = threadIdx.x;

  if (bx < 512) {  // --- fc_w f32->bf16 ---
    int i = bx * 256 + t;
    const float4* p = (const float4*)fc_w + (size_t)i * 2;
    float4 a = p[0], b = p[1];
    *((bf16x8*)WFC + i) = cvt8(a, b);
    return;
  }
  bx -= 512;
  if (bx < 768) {  // --- wtrans x3 (256 blocks per z) ---
    const int z = bx >> 8, rem = bx & 255;
    const float* w = z == 0 ? wq : (z == 1 ? wk : wv);
    const float scale = z == 0 ? 0.125f * 1.4426950408889634f : 1.0f;  // 1/sqrt(DK)*log2e in W_q
    __bf16* o = W3T + (size_t)z * 1048576;
    const int h = rem & 15, d0 = (rem >> 4) * 64;
    const int r = t >> 2, c0 = (t & 3) * 16;
    const float4* s4 = (const float4*)(w + ((size_t)h * 1024 + d0 + r) * 64 + c0);
#pragma unroll
    for (int j = 0; j < 4; ++j) {
      float4 vv = s4[j];
      tile[r][c0 + 4 * j + 0] = vv.x; tile[r][c0 + 4 * j + 1] = vv.y;
      tile[r][c0 + 4 * j + 2] = vv.z; tile[r][c0 + 4 * j + 3] = vv.w;
    }
    __syncthreads();
    __bf16* dst = o + ((size_t)(h * 64 + r)) * 1024 + d0 + c0;
    bf16x8 o0, o1;
#pragma unroll
    for (int j = 0; j < 8; ++j) o0[j] = (__bf16)(tile[c0 + j][r] * scale);
#pragma unroll
    for (int j = 0; j < 8; ++j) o1[j] = (__bf16)(tile[c0 + 8 + j][r] * scale);
    *(bf16x8*)dst = o0;
    *(bf16x8*)(dst + 8) = o1;
    return;
  }
  bx -= 768;
  {  // --- mask -> ballot bits (1024 blocks) ---
    const int wid = bx * 4 + (t >> 6);
    const int lane = t & 63;
#pragma unroll
    for (int i = 0; i < 16; ++i) {
      int widx = wid * 16 + i;                 // (b*16 + kt)*1024 + qrow
      int qrow = widx & 1023;
      int bkt = widx >> 10;
      int b = bkt >> 4, kt = bkt & 15;
      int mval = mask[((size_t)b * 1024 + qrow) * 1024 + kt * 64 + lane];
      unsigned long long bal = __ballot(mval != 0);
      if (lane == 0) bits[widx] = bal;
    }
  }
}

// ---------------- QKV GEMM 128x128, BK=64, fused f32->bf16 A with barrier-fenced T14 ------
// grid = 768 linear; xcd = L&7, wl = xcd*96 + L>>3; bn = wl&7, bm = (wl>>3)&31, z = wl>>8.
// Per iter: [A-loads(kt+1)->regs + B gload_lds(kt+1)] -> 32 MFMA -> barrier ->
//           cvt+ds_write A(kt+1) -> barrier.  __syncthreads is an IR fence: the A loads
//           cannot be sunk to the consumer, so their latency hides under the MFMA phase.
__global__ __launch_bounds__(256, 3) void gemm_qkv(const float* __restrict__ q,
                                                   const float* __restrict__ k,
                                                   const float* __restrict__ v,
                                                   const __bf16* __restrict__ Btbase,
                                                   __bf16* __restrict__ HEADS) {
  // LDS bytes: A single-buf [0,16K); B buf0 [16K,32K) buf1 [32K,48K). Epilogue overlays.
  __shared__ __bf16 SMEM[24576];
  const int L = blockIdx.x;
  const int wl = (L & 7) * 96 + (L >> 3);
  const int bn = wl & 7;
  const int bmz = wl >> 3;          // 0..95
  const int bm = bmz & 31, z = bmz >> 5;
  const float* Af = z == 0 ? q : (z == 1 ? k : v);
  const __bf16* Bt = Btbase + (size_t)z * 1048576;
  const int tid = threadIdx.x, lane = tid & 63;
  const int w = tid >> 6;
  const int wr = (w >> 1) * 64, wc = (w & 1) * 64;
  const int lr = lane & 15, lh = lane >> 4;
  char* smem = (char*)SMEM;
  const int t16 = tid * 16;

  // A reg staging: row rA = tid>>1 (2 threads/row), f32 col base (tid&1)*32; +64 cols per kt
  const int rA = tid >> 1;
  const float* apA = Af + (size_t)(bm * 128 + rA) * 1024 + (tid & 1) * 32;
  // A LDS write offsets: 4x b128, granule G=(tid&1)*4+j, stored G^(rA&7)  (2-way max)
  int awr[4];
#pragma unroll
  for (int j = 0; j < 4; ++j)
    awr[j] = rA * 128 + ((((tid & 1) * 4 + j) ^ (rA & 7)) * 16);

  // B staging via gload_lds: tile 128 rows x 64 bf16 (128B rows), 4 shots of 4KB;
  // source granule pre-swizzled ^(row&7); +128B per kt
  const char* apB = (const char*)Bt + ((size_t)(bn * 128 + (tid >> 3)) * 2048) +
                    (((tid & 7) ^ ((tid >> 3) & 7)) * 16);

#define BSTAGE(buf)                                          \
  do {                                                       \
    char* db = smem + 16384 + (buf) * 16384;                 \
    gload_lds16(apB, db + t16);                              \
    gload_lds16(apB + 65536, db + 4096 + t16);               \
    gload_lds16(apB + 131072, db + 8192 + t16);              \
    gload_lds16(apB + 196608, db + 12288 + t16);             \
    apB += 128;                                              \
  } while (0)

  // fragment read offsets (bytes): row*128 + ((ks*4+lh)^(lr&7))*16   (conflict-free)
  int ard[4][2], brd[4][2];
#pragma unroll
  for (int m = 0; m < 4; ++m)
#pragma unroll
    for (int ks = 0; ks < 2; ++ks) {
      ard[m][ks] = (wr + m * 16 + lr) * 128 + (((ks * 4 + lh) ^ (lr & 7)) * 16);
      brd[m][ks] = (wc + m * 16 + lr) * 128 + (((ks * 4 + lh) ^ (lr & 7)) * 16);
    }

  f32x4 acc[4][4];
#pragma unroll
  for (int m = 0; m < 4; ++m)
#pragma unroll
    for (int n = 0; n < 4; ++n) {
      f32x4 zz = {0.f, 0.f, 0.f, 0.f};
      acc[m][n] = zz;
    }

  // prologue: A(0) regs->cvt->LDS, B(0) gload
  {
    float4 a[8];
#pragma unroll
    for (int j = 0; j < 8; ++j) a[j] = *(const float4*)(apA + j * 4);
#pragma unroll
    for (int j = 0; j < 4; ++j)
      *(bf16x8*)(smem + awr[j]) = cvt8(a[2 * j], a[2 * j + 1]);
  }
  BSTAGE(0);
  __syncthreads();

  for (int kt = 0; kt < 16; ++kt) {
    const int cur = kt & 1;
    float4 a[8];
    if (kt < 15) {
      const float* pa = apA + (size_t)(kt + 1) * 64;
#pragma unroll
      for (int j = 0; j < 8; ++j) a[j] = *(const float4*)(pa + j * 4);
      BSTAGE(cur ^ 1);
    }
    const int bbase = 16384 + cur * 16384;
#pragma unroll
    for (int ks = 0; ks < 2; ++ks) {
      bf16x8 af[4], bfr[4];
#pragma unroll
      for (int m = 0; m < 4; ++m) af[m] = *(const bf16x8*)(smem + ard[m][ks]);
#pragma unroll
      for (int n = 0; n < 4; ++n) bfr[n] = *(const bf16x8*)(smem + bbase + brd[n][ks]);
      __builtin_amdgcn_s_setprio(1);
#pragma unroll
      for (int m = 0; m < 4; ++m)
#pragma unroll
        for (int n = 0; n < 4; ++n) acc[m][n] = MFMA16(af[m], bfr[n], acc[m][n]);
      __builtin_amdgcn_s_setprio(0);
    }
    __syncthreads();                 // fence: protects A overwrite; A/B loads long done
    if (kt < 15) {
#pragma unroll
      for (int j = 0; j < 4; ++j)
        *(bf16x8*)(smem + awr[j]) = cvt8(a[2 * j], a[2 * j + 1]);
    }
    __syncthreads();                 // A(kt+1) visible for next iter
  }
#undef BSTAGE

  if (z == 2) {
    // V^T epilogue: acc -> LDS (transposed, padded stride 132) -> coalesced rows.
    const int hl = w & 1;
    const size_t vtbase = 2ull * 4194304;
    const size_t bb2 = (size_t)(bm >> 3) * 16 + bn * 2;
    const int kkbase = (bm & 7) * 128;
#pragma unroll
    for (int p = 0; p < 2; ++p) {
      if (hl == p) {
#pragma unroll
        for (int m = 0; m < 4; ++m)
#pragma unroll
          for (int n = 0; n < 4; ++n) {
            const int dk = n * 16 + lr;
            const int s = wr + m * 16 + lh * 4;
            bf16x4 pv;
#pragma unroll
            for (int j = 0; j < 4; ++j) pv[j] = (__bf16)acc[m][n][j];
            *(bf16x4*)&SMEM[dk * 132 + s] = pv;
          }
      }
      __syncthreads();
      {
        const int dk = tid >> 2, sc = tid & 3;
        const __bf16* srcp = &SMEM[dk * 132 + sc * 32];
        __bf16* dstp = HEADS + vtbase + ((bb2 + p) * 64 + dk) * 1024 + kkbase + sc * 32;
#pragma unroll
        for (int u = 0; u < 8; ++u) *(bf16x4*)(dstp + u * 4) = *(const bf16x4*)(srcp + u * 4);
      }
      __syncthreads();
    }
    return;
  }

  // Q/K epilogue: 2-pass LDS transpose (stride 132) -> coalesced 64B row chunks
#pragma unroll
  for (int p = 0; p < 2; ++p) {
    if ((w >> 1) == p) {
#pragma unroll
      for (int m = 0; m < 4; ++m)
#pragma unroll
        for (int n = 0; n < 4; ++n)
#pragma unroll
          for (int reg = 0; reg < 4; ++reg)
            SMEM[(m * 16 + lh * 4 + reg) * 132 + wc + n * 16 + lr] = (__bf16)acc[m][n][reg];
    }
    __syncthreads();
    {
      const int rowl = tid >> 2, c0 = (tid & 3) * 32;
      const int row = bm * 128 + p * 64 + rowl;
      const int b = row >> 10, s = row & 1023;
      const int h = bn * 2 + (c0 >> 6), dk0 = c0 & 63;
      __bf16* dst = HEADS + (size_t)z * 4194304 + (((size_t)b * 16 + h) * 1024 + s) * 64 + dk0;
      const __bf16* srcp = &SMEM[rowl * 132 + c0];
#pragma unroll
      for (int u = 0; u < 8; ++u) *(bf16x4*)(dst + u * 4) = *(const bf16x4*)(srcp + u * 4);
    }
    __syncthreads();
  }
}

// ---------------- fc GEMM 64x128 tile, XCD-swizzled, double-buffered ----------------
__global__ __launch_bounds__(256) void gemm_fc64(const __bf16* __restrict__ A,
                                                 const __bf16* __restrict__ Bt,
                                                 float* __restrict__ O,
                                                 const float* __restrict__ resid) {
  // bytes: A0 [0,4K) A1 [4K,8K) B0 [8K,16K) B1 [16K,24K)
  __shared__ __bf16 SMEM[12288];
  const int L = blockIdx.x;
  const int wl = (L & 7) * 64 + (L >> 3);
  const int bn = wl & 7, bm = wl >> 3;   // 8 bn-blocks per bm-panel on same XCD
  const int tid = threadIdx.x, lane = tid & 63;
  const int w = tid >> 6;
  const int wc = w * 32;
  const int lr = lane & 15, lh = lane >> 4;

  const int o0 = tid * 16;
  const int row0 = o0 >> 6, cb = o0 & 63;
  const char* apA = (const char*)A + ((size_t)(bm * 64 + row0) * 1024) * 2 + cb;
  const char* apB0 = (const char*)Bt + ((size_t)(bn * 128 + row0) * 1024) * 2 + cb;
  const char* apB1 = apB0 + 64 * 2048;
  char* smem = (char*)SMEM;

#define FSTAGE(buf)                                         \
  do {                                                      \
    gload_lds16(apA, smem + (buf) * 4096 + o0);             \
    char* dd = smem + 8192 + (buf) * 8192;                  \
    gload_lds16(apB0, dd + o0);                             \
    gload_lds16(apB1, dd + 4096 + o0);                      \
    apA += 64; apB0 += 64; apB1 += 64;                      \
  } while (0)

  f32x4 acc[4][2];
#pragma unroll
  for (int m = 0; m < 4; ++m)
#pragma unroll
    for (int n = 0; n < 2; ++n) {
      f32x4 z = {0.f, 0.f, 0.f, 0.f};
      acc[m][n] = z;
    }

  FSTAGE(0);
  __syncthreads();

  for (int kt = 0; kt < 32; ++kt) {
    const int cur = kt & 1;
    if (kt < 31) FSTAGE(cur ^ 1);
    const int ab = cur * 2048;               // elements
    const int bb = 4096 + cur * 4096;
    bf16x8 af[4], bfr[2];
#pragma unroll
    for (int m = 0; m < 4; ++m) af[m] = *(const bf16x8*)&SMEM[ab + (m * 16 + lr) * 32 + lh * 8];
#pragma unroll
    for (int n = 0; n < 2; ++n)
      bfr[n] = *(const bf16x8*)&SMEM[bb + (wc + n * 16 + lr) * 32 + lh * 8];
    __builtin_amdgcn_s_setprio(1);
#pragma unroll
    for (int m = 0; m < 4; ++m)
#pragma unroll
      for (int n = 0; n < 2; ++n) acc[m][n] = MFMA16(af[m], bfr[n], acc[m][n]);
    __builtin_amdgcn_s_setprio(0);
    __syncthreads();
  }
#undef FSTAGE

#pragma unroll
  for (int m = 0; m < 4; ++m)
#pragma unroll
    for (int n = 0; n < 2; ++n)
#pragma unroll
      for (int reg = 0; reg < 4; ++reg) {
        int row = bm * 64 + m * 16 + lh * 4 + reg;
        int col = bn * 128 + wc + n * 16 + lr;
        size_t idx = (size_t)row * 1024 + col;
        O[idx] = acc[m][n][reg] + resid[idx];
      }
}

// ---------------- flash attention: no-max softmax (scores provably bounded) ----------------
__global__ __launch_bounds__(256, 4) void attn_kernel(const __bf16* __restrict__ HEADS,
                                                      const unsigned long long* __restrict__ m64,
                                                      __bf16* __restrict__ concat) {
  const __bf16* QH = HEADS;
  const __bf16* KH = HEADS + (size_t)M_ * 1024;
  const __bf16* VT = HEADS + (size_t)2 * M_ * 1024;   // [bh][64][1024]
  __shared__ __bf16 Ks[2][2][32 * 64];   // [buf][stream]  4KB each
  __shared__ __bf16 Vs[2][2][64 * 32];   // [buf][stream]  4KB each
  __shared__ unsigned Psw[2][4][256];    // [stream][wave] 1KB each

  // XCD-aware remap: 8 (b,h) groups per xcd, 16 q-tiles each
  const int d = blockIdx.x;            // 0..1023
  const int xcd = d & 7, j = d >> 3;   // j 0..127
  const int grp = xcd * 8 + (j >> 4);  // 0..63
  const int qt = j & 15;               // 64 q-rows per block
  const int h = grp & 15, b = grp >> 4;

  const int tid = threadIdx.x, lane = tid & 63, w = tid >> 6;
  const int lr = lane & 15, lh = lane >> 4;
  const size_t headoff = ((size_t)b * 16 + h) * 65536;
  const char* Kbase = (const char*)(KH + headoff);   // [1024 kk][64 dk], 128B rows
  const char* Vbase = (const char*)(VT + headoff);   // [64 dv][1024 kk], 2048B rows

  // staging source offsets (pre-swizzled global; LDS dest linear = tid*16)
  const int krow = tid >> 3, kg = tid & 7;
  const int kgo = krow * 128 + ((kg ^ (krow & 7)) * 16);
  const int vrow = tid >> 2, vg = tid & 3;
  const int vgo = vrow * 2048 + ((vg ^ ((vrow >> 1) & 3)) * 16);
  const int ldsb = tid * 16;

  // incremental staging pointers (advance per staged tile)
  const char* kpA = Kbase + kgo;
  const char* kpB = Kbase + 65536 + kgo;
  const char* vpA = Vbase + vgo;
  const char* vpB = Vbase + 1024 + vgo;

#define STAGE(buf)                                          \
  do {                                                      \
    gload_lds16(kpA, (char*)Ks[buf][0] + ldsb);             \
    gload_lds16(kpB, (char*)Ks[buf][1] + ldsb);             \
    gload_lds16(vpA, (char*)Vs[buf][0] + ldsb);             \
    gload_lds16(vpB, (char*)Vs[buf][1] + ldsb);             \
    kpA += 4096; kpB += 4096; vpA += 64; vpB += 64;         \
  } while (0)

  const int qrow = qt * 64 + w * 16 + lr;   // this lane's q-row
  bf16x8 qa[2];
  {
    const __bf16* qptr = QH + headoff + (size_t)qrow * 64 + lh * 8;
    qa[0] = *(const bf16x8*)qptr;
    qa[1] = *(const bf16x8*)(qptr + 32);
  }
  f32x4 oacc[4];
#pragma unroll
  for (int g = 0; g < 4; ++g) {
    f32x4 z = {0.f, 0.f, 0.f, 0.f};
    oacc[g] = z;
  }
  float lrun = 0.f;   // lane-partial softmax denominator (reduced only at epilogue)

  // mask: u64 word j (=t>>1) covers tiles 2j,2j+1 (32 kk each); stream B at +8 words
  const unsigned long long* m64A = m64 + (size_t)b * 16384 + qrow;
  const unsigned long long* m64B = m64A + 8192;
  unsigned long long pairA = m64A[0], pairB = m64B[0];
  unsigned long long pairAn = 0, pairBn = 0;

  // hoisted LDS read offsets (u16 units)
  const int vcol = (lh ^ ((lr >> 1) & 3)) * 8;           // V/P granule
  const int pread = lr * 32 + vcol;                      // pa b128
  const int pG = (lr >> 1) & 3;                          // P write swizzle key
  int kread[2][2], vread[4];
#pragma unroll
  for (int n = 0; n < 2; ++n)
#pragma unroll
    for (int h2 = 0; h2 < 2; ++h2) kread[n][h2] = SWZ(n * 16 + lr, h2 * 4 + lh);
#pragma unroll
  for (int g = 0; g < 4; ++g) vread[g] = (g * 16 + lr) * 32 + vcol;

  // prologue: stage tile 0
  STAGE(0);
  __syncthreads();

#pragma unroll 2
  for (int t = 0; t < 16; ++t) {
    const int cur = t & 1;
    if ((t & 1) == 0 && t < 14) {           // prefetch mask pair for tiles t+2,t+3
      pairAn = m64A[((t >> 1) + 1) * 1024];
      pairBn = m64B[((t >> 1) + 1) * 1024];
    }
    const unsigned mwA = (t & 1) ? (unsigned)(pairA >> 32) : (unsigned)pairA;
    const unsigned mwB = (t & 1) ? (unsigned)(pairB >> 32) : (unsigned)pairB;
    if (t < 15) STAGE(cur ^ 1);

    // S^T = K Q^T for both streams (8 MFMA, independent)
    f32x4 sA[2], sB[2];
#pragma unroll
    for (int n = 0; n < 2; ++n) {
      f32x4 z = {0.f, 0.f, 0.f, 0.f};
      sA[n] = z; sB[n] = z;
    }
    __builtin_amdgcn_s_setprio(1);
#pragma unroll
    for (int n = 0; n < 2; ++n)
#pragma unroll
      for (int h2 = 0; h2 < 2; ++h2) {
        bf16x8 kbA = *(const bf16x8*)&Ks[cur][0][kread[n][h2]];
        bf16x8 kbB = *(const bf16x8*)&Ks[cur][1][kread[n][h2]];
        sA[n] = MFMA16(kbA, qa[h2], sA[n]);
        sB[n] = MFMA16(kbB, qa[h2], sB[n]);
      }
    __builtin_amdgcn_s_setprio(0);

    // no-max softmax: p = bit ? 2^s : 0 ; accumulate lane-partial l
#pragma unroll
    for (int n = 0; n < 2; ++n)
#pragma unroll
      for (int r = 0; r < 4; ++r) {
        unsigned bit = (mwA >> (n * 16 + lh * 4 + r)) & 1u;
        float p = bit ? exp2_hw(sA[n][r]) : 0.0f;
        sA[n][r] = p;
        lrun += p;
      }
#pragma unroll
    for (int n = 0; n < 2; ++n)
#pragma unroll
      for (int r = 0; r < 4; ++r) {
        unsigned bit = (mwB >> (n * 16 + lh * 4 + r)) & 1u;
        float p = bit ? exp2_hw(sB[n][r]) : 0.0f;
        sB[n][r] = p;
        lrun += p;
      }

    // pack P pairs -> LDS (swizzled), read back A-fragments
#pragma unroll
    for (int n = 0; n < 2; ++n) {
      bf16x2 p0, p1;
      p0[0] = (__bf16)sA[n][0]; p0[1] = (__bf16)sA[n][1];
      p1[0] = (__bf16)sA[n][2]; p1[1] = (__bf16)sA[n][3];
      int G = n * 2 + (lh >> 1);
      int addr = lr * 16 + ((G ^ pG) * 4) + (lh & 1) * 2;
      u32x2 wv;
      wv[0] = __builtin_bit_cast(unsigned, p0);
      wv[1] = __builtin_bit_cast(unsigned, p1);
      *(u32x2*)&Psw[0][w][addr] = wv;
    }
#pragma unroll
    for (int n = 0; n < 2; ++n) {
      bf16x2 p0, p1;
      p0[0] = (__bf16)sB[n][0]; p0[1] = (__bf16)sB[n][1];
      p1[0] = (__bf16)sB[n][2]; p1[1] = (__bf16)sB[n][3];
      int G = n * 2 + (lh >> 1);
      int addr = lr * 16 + ((G ^ pG) * 4) + (lh & 1) * 2;
      u32x2 wv;
      wv[0] = __builtin_bit_cast(unsigned, p0);
      wv[1] = __builtin_bit_cast(unsigned, p1);
      *(u32x2*)&Psw[1][w][addr] = wv;
    }
    bf16x8 paA = *(const bf16x8*)&((const __bf16*)Psw[0][w])[pread];
    bf16x8 paB = *(const bf16x8*)&((const __bf16*)Psw[1][w])[pread];

    // O += P V, both streams into ONE accumulator (same scale: no max shift)
    __builtin_amdgcn_s_setprio(1);
#pragma unroll
    for (int g = 0; g < 4; ++g) {
      bf16x8 vbA = *(const bf16x8*)&Vs[cur][0][vread[g]];
      bf16x8 vbB = *(const bf16x8*)&Vs[cur][1][vread[g]];
      oacc[g] = MFMA16(paA, vbA, oacc[g]);
      oacc[g] = MFMA16(paB, vbB, oacc[g]);
    }
    __builtin_amdgcn_s_setprio(0);
    if (t & 1) { pairA = pairAn; pairB = pairBn; }
    __syncthreads();
  }
#undef STAGE

  // epilogue: reduce l across lh groups (once), normalize, store
  lrun += __shfl_xor(lrun, 16, 64);
  lrun += __shfl_xor(lrun, 32, 64);
  const float linv = 1.0f / (lrun + 1e-30f);
  const int qg0 = qt * 64 + w * 16 + lh * 4;
#pragma unroll
  for (int r = 0; r < 4; ++r) {
    const float ir = __shfl(linv, (lane & 48) | (lh * 4 + r), 64);
#pragma unroll
    for (int g = 0; g < 4; ++g)
      concat[((size_t)b * 1024 + qg0 + r) * 1024 + h * 64 + g * 16 + lr] =
          (__bf16)(oacc[g][r] * ir);
  }
}

// ---------------- LayerNorm ----------------
__global__ __launch_bounds__(256) void ln_kernel(const float* __restrict__ in,
                                                 const float* __restrict__ gam,
                                                 const float* __restrict__ bet,
                                                 float* __restrict__ out) {
  const int row = blockIdx.x, t = threadIdx.x;
  const float4* x4 = (const float4*)(in + (size_t)row * 1024);
  float4 v = x4[t];
  float s = v.x + v.y + v.z + v.w;
  float sq = v.x * v.x + v.y * v.y + v.z * v.z + v.w * v.w;
#pragma unroll
  for (int off = 1; off < 64; off <<= 1) {
    s += __shfl_xor(s, off, 64);
    sq += __shfl_xor(sq, off, 64);
  }
  __shared__ float red[8];
  const int w = t >> 6, lane = t & 63;
  if (lane == 0) { red[w] = s; red[4 + w] = sq; }
  __syncthreads();
  s = red[0] + red[1] + red[2] + red[3];
  sq = red[4] + red[5] + red[6] + red[7];
  const float mu = s * (1.0f / 1024.0f);
  const float var = sq * (1.0f / 1024.0f) - mu * mu;
  const float rstd = rsqrtf(var + 1e-6f);
  float4 g4 = ((const float4*)gam)[t];
  float4 b4 = ((const float4*)bet)[t];
  float4 o;
  o.x = (v.x - mu) * rstd * g4.x + b4.x;
  o.y = (v.y - mu) * rstd * g4.y + b4.y;
  o.z = (v.z - mu) * rstd * g4.z + b4.z;
  o.w = (v.w - mu) * rstd * g4.w + b4.w;
  ((float4*)(out + (size_t)row * 1024))[t] = o;
}

extern "C" void kernel_launch(void* const* d_in, const int* in_sizes, int n_in,
                              void* d_out, int out_size, void* d_ws, size_t ws_size,
                              hipStream_t stream) {
  (void)in_sizes; (void)n_in; (void)out_size; (void)ws_size;
  const float* q = (const float*)d_in[0];
  const float* k = (const float*)d_in[1];
  const float* v = (const float*)d_in[2];
  const int* mask = (const int*)d_in[3];
  const float* wq = (const float*)d_in[4];
  const float* wk = (const float*)d_in[5];
  const float* wv = (const float*)d_in[6];
  const float* fc_w = (const float*)d_in[7];
  const float* ln_g = (const float*)d_in[8];
  const float* ln_b = (const float*)d_in[9];
  float* out = (float*)d_out;

  // workspace layout (~80 MB; QKVBF region unused)
  __bf16* QKVBF = (__bf16*)d_ws;                       // (unused, kept for layout stability)
  __bf16* W3T   = QKVBF + 3ull * 4194304;              // 3 * 1048576 bf16
  __bf16* WFC   = W3T + 3ull * 1048576;                // 1048576 bf16
  __bf16* HEADS = WFC + 1048576;                       // 3 * 4194304 bf16 (V region = V^T)
  __bf16* CONCAT = HEADS + 3ull * 4194304;             // 4194304 bf16
  float* OUT1 = (float*)(CONCAT + 4194304);            // 4194304 f32
  // mask bits alias OUT1 (attn reads them BEFORE gemm_fc overwrites OUT1)
  unsigned long long* MASKB = (unsigned long long*)OUT1;   // 65536 u64 = 512 KB

  prep<<<2304, 256, 0, stream>>>(fc_w, wq, wk, wv, mask, WFC, W3T, MASKB);
  gemm_qkv<<<768, 256, 0, stream>>>(q, k, v, W3T, HEADS);
  attn_kernel<<<1024, 256, 0, stream>>>(HEADS, MASKB, CONCAT);
  gemm_fc64<<<512, 256, 0, stream>>>(CONCAT, WFC, OUT1, q);
  ln_kernel<<<4096, 256, 0, stream>>>(OUT1, ln_g, ln_b, out);
}

// Round 17
// 111.276 us; speedup vs baseline: 1.2753x; 1.2753x over previous
//
#include <hip/hip_runtime.h>
#include <hip/hip_bf16.h>

typedef __bf16 bf16x8 __attribute__((ext_vector_type(8)));
typedef __bf16 bf16x4 __attribute__((ext_vector_type(4)));
typedef __bf16 bf16x2 __attribute__((ext_vector_type(2)));
typedef float f32x4 __attribute__((ext_vector_type(4)));
typedef unsigned int u32x2 __attribute__((ext_vector_type(2)));

#define MFMA16(a, b, c) __builtin_amdgcn_mfma_f32_16x16x32_bf16(a, b, c, 0, 0, 0)

static constexpr int M_ = 4096;     // B*S rows

__device__ __forceinline__ void gload_lds16(const void* g, void* l) {
  __builtin_amdgcn_global_load_lds((const __attribute__((address_space(1))) void*)g,
                                   (__attribute__((address_space(3))) void*)l, 16, 0, 0);
}

// single-instruction 2^x (inputs bounded |x|<~12 here; no denorm fixup needed)
__device__ __forceinline__ float exp2_hw(float x) {
  float r;
  asm("v_exp_f32 %0, %1" : "=v"(r) : "v"(x));
  return r;
}

__device__ __forceinline__ bf16x8 cvt8(float4 x, float4 y) {
  bf16x8 o;
  o[0] = (__bf16)x.x; o[1] = (__bf16)x.y; o[2] = (__bf16)x.z; o[3] = (__bf16)x.w;
  o[4] = (__bf16)y.x; o[5] = (__bf16)y.y; o[6] = (__bf16)y.z; o[7] = (__bf16)y.w;
  return o;
}

// swizzled LDS u16 index for 64-col bf16 tiles (128B rows, 8 granules):
// stored granule = logical granule ^ (row & 7)
#define SWZ(rowv, c16) (((rowv) * 64) + (((c16) ^ ((rowv) & 7)) * 8))

// ---------------- fused prep: cvt fc_w, wtrans x3, mask bits ----------------
__global__ __launch_bounds__(256) void prep(const float* __restrict__ fc_w,
                                            const float* __restrict__ wq,
                                            const float* __restrict__ wk,
                                            const float* __restrict__ wv,
                                            const int* __restrict__ mask,
                                            __bf16* __restrict__ WFC,
                                            __bf16* __restrict__ W3T,
                                            unsigned long long* __restrict__ bits) {
  __shared__ float tile[64][65];
  int bx = blockIdx.x;
  const int t = threadIdx.x;

  if (bx < 512) {  // --- fc_w f32->bf16 ---
    int i = bx * 256 + t;
    const float4* p = (const float4*)fc_w + (size_t)i * 2;
    float4 a = p[0], b = p[1];
    *((bf16x8*)WFC + i) = cvt8(a, b);
    return;
  }
  bx -= 512;
  if (bx < 768) {  // --- wtrans x3 (256 blocks per z) ---
    const int z = bx >> 8, rem = bx & 255;
    const float* w = z == 0 ? wq : (z == 1 ? wk : wv);
    const float scale = z == 0 ? 0.125f * 1.4426950408889634f : 1.0f;  // 1/sqrt(DK)*log2e in W_q
    __bf16* o = W3T + (size_t)z * 1048576;
    const int h = rem & 15, d0 = (rem >> 4) * 64;
    const int r = t >> 2, c0 = (t & 3) * 16;
    const float4* s4 = (const float4*)(w + ((size_t)h * 1024 + d0 + r) * 64 + c0);
#pragma unroll
    for (int j = 0; j < 4; ++j) {
      float4 vv = s4[j];
      tile[r][c0 + 4 * j + 0] = vv.x; tile[r][c0 + 4 * j + 1] = vv.y;
      tile[r][c0 + 4 * j + 2] = vv.z; tile[r][c0 + 4 * j + 3] = vv.w;
    }
    __syncthreads();
    __bf16* dst = o + ((size_t)(h * 64 + r)) * 1024 + d0 + c0;
    bf16x8 o0, o1;
#pragma unroll
    for (int j = 0; j < 8; ++j) o0[j] = (__bf16)(tile[c0 + j][r] * scale);
#pragma unroll
    for (int j = 0; j < 8; ++j) o1[j] = (__bf16)(tile[c0 + 8 + j][r] * scale);
    *(bf16x8*)dst = o0;
    *(bf16x8*)(dst + 8) = o1;
    return;
  }
  bx -= 768;
  {  // --- mask -> ballot bits (1024 blocks) ---
    const int wid = bx * 4 + (t >> 6);
    const int lane = t & 63;
#pragma unroll
    for (int i = 0; i < 16; ++i) {
      int widx = wid * 16 + i;                 // (b*16 + kt)*1024 + qrow
      int qrow = widx & 1023;
      int bkt = widx >> 10;
      int b = bkt >> 4, kt = bkt & 15;
      int mval = mask[((size_t)b * 1024 + qrow) * 1024 + kt * 64 + lane];
      unsigned long long bal = __ballot(mval != 0);
      if (lane == 0) bits[widx] = bal;
    }
  }
}

// ---------------- QKV GEMM 128x128, XCD-swizzled, f32 A reg-staged (r12 form) ----------------
// grid = 768 linear; xcd = L&7, wl = xcd*96 + L>>3; bn = wl&7, bm = (wl>>3)&31, z = wl>>8.
__global__ __launch_bounds__(256) void gemm_qkv(const float* __restrict__ q,
                                                const float* __restrict__ k,
                                                const float* __restrict__ v,
                                                const __bf16* __restrict__ Btbase,
                                                __bf16* __restrict__ HEADS) {
  // bytes: Abuf0 [0,8K) Abuf1 [8K,16K) Bbuf0 [16K,24K) Bbuf1 [24K,32K). Epilogue Tr overlays.
  __shared__ __bf16 SMEM[16384];
  const int L = blockIdx.x;
  const int wl = (L & 7) * 96 + (L >> 3);
  const int bn = wl & 7;
  const int bmz = wl >> 3;          // 0..95
  const int bm = bmz & 31, z = bmz >> 5;
  const float* Af = z == 0 ? q : (z == 1 ? k : v);
  const __bf16* Bt = Btbase + (size_t)z * 1048576;
  const int tid = threadIdx.x, lane = tid & 63;
  const int w = tid >> 6;
  const int wr = (w >> 1) * 64, wc = (w & 1) * 64;
  const int lr = lane & 15, lh = lane >> 4;

  // A reg-staging: thread t loads rows (t>>2) and (t>>2)+64, cols (t&3)*8..+8 f32 (32B x2)
  const int rowA = tid >> 2, colf = (tid & 3) * 8;
  const float* gA0 = Af + (size_t)(bm * 128 + rowA) * 1024 + colf;
  const float* gA1 = gA0 + 64 * 1024;
  // B staging via gload_lds: shot covers 64 rows (4KB), +64B per kt
  const int o0 = tid * 16;
  const int row0 = o0 >> 6, cb = o0 & 63;
  const char* apB0 = (const char*)Bt + ((size_t)(bn * 128 + row0) * 1024) * 2 + cb;
  const char* apB1 = apB0 + 64 * 2048;
  char* smemB = (char*)SMEM + 16384;

#define BSTAGE(buf)                                         \
  do {                                                      \
    char* dd = smemB + (buf) * 8192;                        \
    gload_lds16(apB0, dd + o0);                             \
    gload_lds16(apB1, dd + 4096 + o0);                      \
    apB0 += 64; apB1 += 64;                                 \
  } while (0)

  f32x4 acc[4][4];
#pragma unroll
  for (int m = 0; m < 4; ++m)
#pragma unroll
    for (int n = 0; n < 4; ++n) {
      f32x4 zz = {0.f, 0.f, 0.f, 0.f};
      acc[m][n] = zz;
    }

  // prologue: stage tile 0
  {
    float4 a0 = *(const float4*)gA0, a1 = *(const float4*)(gA0 + 4);
    float4 b0 = *(const float4*)gA1, b1 = *(const float4*)(gA1 + 4);
    gA0 += 32; gA1 += 32;
    *(bf16x8*)((char*)SMEM + o0) = cvt8(a0, a1);
    *(bf16x8*)((char*)SMEM + 4096 + o0) = cvt8(b0, b1);
  }
  BSTAGE(0);
  __syncthreads();

  for (int kt = 0; kt < 32; ++kt) {
    const int cur = kt & 1;
    float4 a0, a1, b0, b1;
    if (kt < 31) {
      a0 = *(const float4*)gA0; a1 = *(const float4*)(gA0 + 4);
      b0 = *(const float4*)gA1; b1 = *(const float4*)(gA1 + 4);
      gA0 += 32; gA1 += 32;
      BSTAGE(cur ^ 1);
    }
    __builtin_amdgcn_sched_barrier(0);   // loads stay above; compute below
    const int ab = cur * 4096;               // elements
    const int bb = 8192 + cur * 4096;
    bf16x8 af[4], bfr[4];
#pragma unroll
    for (int m = 0; m < 4; ++m)
      af[m] = *(const bf16x8*)&SMEM[ab + (wr + m * 16 + lr) * 32 + lh * 8];
#pragma unroll
    for (int n = 0; n < 4; ++n)
      bfr[n] = *(const bf16x8*)&SMEM[bb + (wc + n * 16 + lr) * 32 + lh * 8];
    __builtin_amdgcn_s_setprio(1);
#pragma unroll
    for (int m = 0; m < 4; ++m)
#pragma unroll
      for (int n = 0; n < 4; ++n) acc[m][n] = MFMA16(af[m], bfr[n], acc[m][n]);
    __builtin_amdgcn_s_setprio(0);
    __builtin_amdgcn_sched_barrier(0);   // cvt+write stays below MFMA
    if (kt < 31) {
      char* dA = (char*)SMEM + (cur ^ 1) * 8192;
      *(bf16x8*)(dA + o0) = cvt8(a0, a1);
      *(bf16x8*)(dA + 4096 + o0) = cvt8(b0, b1);
    }
    __syncthreads();
  }
#undef BSTAGE

  if (z == 2) {
    // V^T epilogue: acc -> LDS (transposed, padded stride 132) -> coalesced rows.
    const int hl = w & 1;
    const size_t vtbase = 2ull * 4194304;
    const size_t bb2 = (size_t)(bm >> 3) * 16 + bn * 2;
    const int kkbase = (bm & 7) * 128;
#pragma unroll
    for (int p = 0; p < 2; ++p) {
      if (hl == p) {
#pragma unroll
        for (int m = 0; m < 4; ++m)
#pragma unroll
          for (int n = 0; n < 4; ++n) {
            const int dk = n * 16 + lr;
            const int s = wr + m * 16 + lh * 4;
            bf16x4 pv;
#pragma unroll
            for (int j = 0; j < 4; ++j) pv[j] = (__bf16)acc[m][n][j];
            *(bf16x4*)&SMEM[dk * 132 + s] = pv;
          }
      }
      __syncthreads();
      {
        const int dk = tid >> 2, sc = tid & 3;
        const __bf16* srcp = &SMEM[dk * 132 + sc * 32];
        __bf16* dstp = HEADS + vtbase + ((bb2 + p) * 64 + dk) * 1024 + kkbase + sc * 32;
#pragma unroll
        for (int u = 0; u < 8; ++u) *(bf16x4*)(dstp + u * 4) = *(const bf16x4*)(srcp + u * 4);
      }
      __syncthreads();
    }
    return;
  }

  // Q/K epilogue: 2-pass LDS transpose (stride 132) -> coalesced 64B row chunks
#pragma unroll
  for (int p = 0; p < 2; ++p) {
    if ((w >> 1) == p) {
#pragma unroll
      for (int m = 0; m < 4; ++m)
#pragma unroll
        for (int n = 0; n < 4; ++n)
#pragma unroll
          for (int reg = 0; reg < 4; ++reg)
            SMEM[(m * 16 + lh * 4 + reg) * 132 + wc + n * 16 + lr] = (__bf16)acc[m][n][reg];
    }
    __syncthreads();
    {
      const int rowl = tid >> 2, c0 = (tid & 3) * 32;
      const int row = bm * 128 + p * 64 + rowl;
      const int b = row >> 10, s = row & 1023;
      const int h = bn * 2 + (c0 >> 6), dk0 = c0 & 63;
      __bf16* dst = HEADS + (size_t)z * 4194304 + (((size_t)b * 16 + h) * 1024 + s) * 64 + dk0;
      const __bf16* srcp = &SMEM[rowl * 132 + c0];
#pragma unroll
      for (int u = 0; u < 8; ++u) *(bf16x4*)(dst + u * 4) = *(const bf16x4*)(srcp + u * 4);
    }
    __syncthreads();
  }
}

// ---------------- fc GEMM 64x128 tile, XCD-swizzled, double-buffered; bf16 output --------
__global__ __launch_bounds__(256) void gemm_fc64(const __bf16* __restrict__ A,
                                                 const __bf16* __restrict__ Bt,
                                                 __bf16* __restrict__ O,
                                                 const float* __restrict__ resid) {
  // bytes: A0 [0,4K) A1 [4K,8K) B0 [8K,16K) B1 [16K,24K)
  __shared__ __bf16 SMEM[12288];
  const int L = blockIdx.x;
  const int wl = (L & 7) * 64 + (L >> 3);
  const int bn = wl & 7, bm = wl >> 3;   // 8 bn-blocks per bm-panel on same XCD
  const int tid = threadIdx.x, lane = tid & 63;
  const int w = tid >> 6;
  const int wc = w * 32;
  const int lr = lane & 15, lh = lane >> 4;

  const int o0 = tid * 16;
  const int row0 = o0 >> 6, cb = o0 & 63;
  const char* apA = (const char*)A + ((size_t)(bm * 64 + row0) * 1024) * 2 + cb;
  const char* apB0 = (const char*)Bt + ((size_t)(bn * 128 + row0) * 1024) * 2 + cb;
  const char* apB1 = apB0 + 64 * 2048;
  char* smem = (char*)SMEM;

#define FSTAGE(buf)                                         \
  do {                                                      \
    gload_lds16(apA, smem + (buf) * 4096 + o0);             \
    char* dd = smem + 8192 + (buf) * 8192;                  \
    gload_lds16(apB0, dd + o0);                             \
    gload_lds16(apB1, dd + 4096 + o0);                      \
    apA += 64; apB0 += 64; apB1 += 64;                      \
  } while (0)

  f32x4 acc[4][2];
#pragma unroll
  for (int m = 0; m < 4; ++m)
#pragma unroll
    for (int n = 0; n < 2; ++n) {
      f32x4 z = {0.f, 0.f, 0.f, 0.f};
      acc[m][n] = z;
    }

  FSTAGE(0);
  __syncthreads();

  for (int kt = 0; kt < 32; ++kt) {
    const int cur = kt & 1;
    if (kt < 31) FSTAGE(cur ^ 1);
    const int ab = cur * 2048;               // elements
    const int bb = 4096 + cur * 4096;
    bf16x8 af[4], bfr[2];
#pragma unroll
    for (int m = 0; m < 4; ++m) af[m] = *(const bf16x8*)&SMEM[ab + (m * 16 + lr) * 32 + lh * 8];
#pragma unroll
    for (int n = 0; n < 2; ++n)
      bfr[n] = *(const bf16x8*)&SMEM[bb + (wc + n * 16 + lr) * 32 + lh * 8];
    __builtin_amdgcn_s_setprio(1);
#pragma unroll
    for (int m = 0; m < 4; ++m)
#pragma unroll
      for (int n = 0; n < 2; ++n) acc[m][n] = MFMA16(af[m], bfr[n], acc[m][n]);
    __builtin_amdgcn_s_setprio(0);
    __syncthreads();
  }
#undef FSTAGE

#pragma unroll
  for (int m = 0; m < 4; ++m)
#pragma unroll
    for (int n = 0; n < 2; ++n)
#pragma unroll
      for (int reg = 0; reg < 4; ++reg) {
        int row = bm * 64 + m * 16 + lh * 4 + reg;
        int col = bn * 128 + wc + n * 16 + lr;
        size_t idx = (size_t)row * 1024 + col;
        O[idx] = (__bf16)(acc[m][n][reg] + resid[idx]);
      }
}

// ---------------- flash attention: no-max softmax (scores provably bounded) ----------------
__global__ __launch_bounds__(256, 4) void attn_kernel(const __bf16* __restrict__ HEADS,
                                                      const unsigned long long* __restrict__ m64,
                                                      __bf16* __restrict__ concat) {
  const __bf16* QH = HEADS;
  const __bf16* KH = HEADS + (size_t)M_ * 1024;
  const __bf16* VT = HEADS + (size_t)2 * M_ * 1024;   // [bh][64][1024]
  __shared__ __bf16 Ks[2][2][32 * 64];   // [buf][stream]  4KB each
  __shared__ __bf16 Vs[2][2][64 * 32];   // [buf][stream]  4KB each
  __shared__ unsigned Psw[2][4][256];    // [stream][wave] 1KB each

  // XCD-aware remap: 8 (b,h) groups per xcd, 16 q-tiles each
  const int d = blockIdx.x;            // 0..1023
  const int xcd = d & 7, j = d >> 3;   // j 0..127
  const int grp = xcd * 8 + (j >> 4);  // 0..63
  const int qt = j & 15;               // 64 q-rows per block
  const int h = grp & 15, b = grp >> 4;

  const int tid = threadIdx.x, lane = tid & 63, w = tid >> 6;
  const int lr = lane & 15, lh = lane >> 4;
  const size_t headoff = ((size_t)b * 16 + h) * 65536;
  const char* Kbase = (const char*)(KH + headoff);   // [1024 kk][64 dk], 128B rows
  const char* Vbase = (const char*)(VT + headoff);   // [64 dv][1024 kk], 2048B rows

  // staging source offsets (pre-swizzled global; LDS dest linear = tid*16)
  const int krow = tid >> 3, kg = tid & 7;
  const int kgo = krow * 128 + ((kg ^ (krow & 7)) * 16);
  const int vrow = tid >> 2, vg = tid & 3;
  const int vgo = vrow * 2048 + ((vg ^ ((vrow >> 1) & 3)) * 16);
  const int ldsb = tid * 16;

  // incremental staging pointers (advance per staged tile)
  const char* kpA = Kbase + kgo;
  const char* kpB = Kbase + 65536 + kgo;
  const char* vpA = Vbase + vgo;
  const char* vpB = Vbase + 1024 + vgo;

#define STAGE(buf)                                          \
  do {                                                      \
    gload_lds16(kpA, (char*)Ks[buf][0] + ldsb);             \
    gload_lds16(kpB, (char*)Ks[buf][1] + ldsb);             \
    gload_lds16(vpA, (char*)Vs[buf][0] + ldsb);             \
    gload_lds16(vpB, (char*)Vs[buf][1] + ldsb);             \
    kpA += 4096; kpB += 4096; vpA += 64; vpB += 64;         \
  } while (0)

  const int qrow = qt * 64 + w * 16 + lr;   // this lane's q-row
  bf16x8 qa[2];
  {
    const __bf16* qptr = QH + headoff + (size_t)qrow * 64 + lh * 8;
    qa[0] = *(const bf16x8*)qptr;
    qa[1] = *(const bf16x8*)(qptr + 32);
  }
  f32x4 oacc[4];
#pragma unroll
  for (int g = 0; g < 4; ++g) {
    f32x4 z = {0.f, 0.f, 0.f, 0.f};
    oacc[g] = z;
  }
  float lrun = 0.f;   // lane-partial softmax denominator (reduced only at epilogue)

  // mask: u64 word j (=t>>1) covers tiles 2j,2j+1 (32 kk each); stream B at +8 words
  const unsigned long long* m64A = m64 + (size_t)b * 16384 + qrow;
  const unsigned long long* m64B = m64A + 8192;
  unsigned long long pairA = m64A[0], pairB = m64B[0];
  unsigned long long pairAn = 0, pairBn = 0;

  // hoisted LDS read offsets (u16 units)
  const int vcol = (lh ^ ((lr >> 1) & 3)) * 8;           // V/P granule
  const int pread = lr * 32 + vcol;                      // pa b128
  const int pG = (lr >> 1) & 3;                          // P write swizzle key
  int kread[2][2], vread[4];
#pragma unroll
  for (int n = 0; n < 2; ++n)
#pragma unroll
    for (int h2 = 0; h2 < 2; ++h2) kread[n][h2] = SWZ(n * 16 + lr, h2 * 4 + lh);
#pragma unroll
  for (int g = 0; g < 4; ++g) vread[g] = (g * 16 + lr) * 32 + vcol;

  // prologue: stage tile 0
  STAGE(0);
  __syncthreads();

#pragma unroll 2
  for (int t = 0; t < 16; ++t) {
    const int cur = t & 1;
    if ((t & 1) == 0 && t < 14) {           // prefetch mask pair for tiles t+2,t+3
      pairAn = m64A[((t >> 1) + 1) * 1024];
      pairBn = m64B[((t >> 1) + 1) * 1024];
    }
    const unsigned mwA = (t & 1) ? (unsigned)(pairA >> 32) : (unsigned)pairA;
    const unsigned mwB = (t & 1) ? (unsigned)(pairB >> 32) : (unsigned)pairB;
    if (t < 15) STAGE(cur ^ 1);

    // S^T = K Q^T for both streams (8 MFMA, independent)
    f32x4 sA[2], sB[2];
#pragma unroll
    for (int n = 0; n < 2; ++n) {
      f32x4 z = {0.f, 0.f, 0.f, 0.f};
      sA[n] = z; sB[n] = z;
    }
    __builtin_amdgcn_s_setprio(1);
#pragma unroll
    for (int n = 0; n < 2; ++n)
#pragma unroll
      for (int h2 = 0; h2 < 2; ++h2) {
        bf16x8 kbA = *(const bf16x8*)&Ks[cur][0][kread[n][h2]];
        bf16x8 kbB = *(const bf16x8*)&Ks[cur][1][kread[n][h2]];
        sA[n] = MFMA16(kbA, qa[h2], sA[n]);
        sB[n] = MFMA16(kbB, qa[h2], sB[n]);
      }
    __builtin_amdgcn_s_setprio(0);

    // no-max softmax: p = bit ? 2^s : 0 ; accumulate lane-partial l
#pragma unroll
    for (int n = 0; n < 2; ++n)
#pragma unroll
      for (int r = 0; r < 4; ++r) {
        unsigned bit = (mwA >> (n * 16 + lh * 4 + r)) & 1u;
        float p = bit ? exp2_hw(sA[n][r]) : 0.0f;
        sA[n][r] = p;
        lrun += p;
      }
#pragma unroll
    for (int n = 0; n < 2; ++n)
#pragma unroll
      for (int r = 0; r < 4; ++r) {
        unsigned bit = (mwB >> (n * 16 + lh * 4 + r)) & 1u;
        float p = bit ? exp2_hw(sB[n][r]) : 0.0f;
        sB[n][r] = p;
        lrun += p;
      }

    // pack P pairs -> LDS (swizzled), read back A-fragments
#pragma unroll
    for (int n = 0; n < 2; ++n) {
      bf16x2 p0, p1;
      p0[0] = (__bf16)sA[n][0]; p0[1] = (__bf16)sA[n][1];
      p1[0] = (__bf16)sA[n][2]; p1[1] = (__bf16)sA[n][3];
      int G = n * 2 + (lh >> 1);
      int addr = lr * 16 + ((G ^ pG) * 4) + (lh & 1) * 2;
      u32x2 wv;
      wv[0] = __builtin_bit_cast(unsigned, p0);
      wv[1] = __builtin_bit_cast(unsigned, p1);
      *(u32x2*)&Psw[0][w][addr] = wv;
    }
#pragma unroll
    for (int n = 0; n < 2; ++n) {
      bf16x2 p0, p1;
      p0[0] = (__bf16)sB[n][0]; p0[1] = (__bf16)sB[n][1];
      p1[0] = (__bf16)sB[n][2]; p1[1] = (__bf16)sB[n][3];
      int G = n * 2 + (lh >> 1);
      int addr = lr * 16 + ((G ^ pG) * 4) + (lh & 1) * 2;
      u32x2 wv;
      wv[0] = __builtin_bit_cast(unsigned, p0);
      wv[1] = __builtin_bit_cast(unsigned, p1);
      *(u32x2*)&Psw[1][w][addr] = wv;
    }
    bf16x8 paA = *(const bf16x8*)&((const __bf16*)Psw[0][w])[pread];
    bf16x8 paB = *(const bf16x8*)&((const __bf16*)Psw[1][w])[pread];

    // O += P V, both streams into ONE accumulator (same scale: no max shift)
    __builtin_amdgcn_s_setprio(1);
#pragma unroll
    for (int g = 0; g < 4; ++g) {
      bf16x8 vbA = *(const bf16x8*)&Vs[cur][0][vread[g]];
      bf16x8 vbB = *(const bf16x8*)&Vs[cur][1][vread[g]];
      oacc[g] = MFMA16(paA, vbA, oacc[g]);
      oacc[g] = MFMA16(paB, vbB, oacc[g]);
    }
    __builtin_amdgcn_s_setprio(0);
    if (t & 1) { pairA = pairAn; pairB = pairBn; }
    __syncthreads();
  }
#undef STAGE

  // epilogue: reduce l across lh groups (once), normalize, store
  lrun += __shfl_xor(lrun, 16, 64);
  lrun += __shfl_xor(lrun, 32, 64);
  const float linv = 1.0f / (lrun + 1e-30f);
  const int qg0 = qt * 64 + w * 16 + lh * 4;
#pragma unroll
  for (int r = 0; r < 4; ++r) {
    const float ir = __shfl(linv, (lane & 48) | (lh * 4 + r), 64);
#pragma unroll
    for (int g = 0; g < 4; ++g)
      concat[((size_t)b * 1024 + qg0 + r) * 1024 + h * 64 + g * 16 + lr] =
          (__bf16)(oacc[g][r] * ir);
  }
}

// ---------------- LayerNorm (bf16 input) ----------------
__global__ __launch_bounds__(256) void ln_kernel(const __bf16* __restrict__ in,
                                                 const float* __restrict__ gam,
                                                 const float* __restrict__ bet,
                                                 float* __restrict__ out) {
  const int row = blockIdx.x, t = threadIdx.x;
  bf16x4 xv = *((const bf16x4*)(in + (size_t)row * 1024) + t);
  float x0 = (float)xv[0], x1 = (float)xv[1], x2 = (float)xv[2], x3 = (float)xv[3];
  float s = x0 + x1 + x2 + x3;
  float sq = x0 * x0 + x1 * x1 + x2 * x2 + x3 * x3;
#pragma unroll
  for (int off = 1; off < 64; off <<= 1) {
    s += __shfl_xor(s, off, 64);
    sq += __shfl_xor(sq, off, 64);
  }
  __shared__ float red[8];
  const int w = t >> 6, lane = t & 63;
  if (lane == 0) { red[w] = s; red[4 + w] = sq; }
  __syncthreads();
  s = red[0] + red[1] + red[2] + red[3];
  sq = red[4] + red[5] + red[6] + red[7];
  const float mu = s * (1.0f / 1024.0f);
  const float var = sq * (1.0f / 1024.0f) - mu * mu;
  const float rstd = rsqrtf(var + 1e-6f);
  float4 g4 = ((const float4*)gam)[t];
  float4 b4 = ((const float4*)bet)[t];
  float4 o;
  o.x = (x0 - mu) * rstd * g4.x + b4.x;
  o.y = (x1 - mu) * rstd * g4.y + b4.y;
  o.z = (x2 - mu) * rstd * g4.z + b4.z;
  o.w = (x3 - mu) * rstd * g4.w + b4.w;
  ((float4*)(out + (size_t)row * 1024))[t] = o;
}

extern "C" void kernel_launch(void* const* d_in, const int* in_sizes, int n_in,
                              void* d_out, int out_size, void* d_ws, size_t ws_size,
                              hipStream_t stream) {
  (void)in_sizes; (void)n_in; (void)out_size; (void)ws_size;
  const float* q = (const float*)d_in[0];
  const float* k = (const float*)d_in[1];
  const float* v = (const float*)d_in[2];
  const int* mask = (const int*)d_in[3];
  const float* wq = (const float*)d_in[4];
  const float* wk = (const float*)d_in[5];
  const float* wv = (const float*)d_in[6];
  const float* fc_w = (const float*)d_in[7];
  const float* ln_g = (const float*)d_in[8];
  const float* ln_b = (const float*)d_in[9];
  float* out = (float*)d_out;

  // workspace layout (~80 MB; QKVBF region unused)
  __bf16* QKVBF = (__bf16*)d_ws;                       // (unused, kept for layout stability)
  __bf16* W3T   = QKVBF + 3ull * 4194304;              // 3 * 1048576 bf16
  __bf16* WFC   = W3T + 3ull * 1048576;                // 1048576 bf16
  __bf16* HEADS = WFC + 1048576;                       // 3 * 4194304 bf16 (V region = V^T)
  __bf16* CONCAT = HEADS + 3ull * 4194304;             // 4194304 bf16
  __bf16* OUT1B = CONCAT + 4194304;                    // 4194304 bf16 (pre-LN, fused resid)
  // mask bits alias the region after OUT1B (attn reads them BEFORE gemm_fc writes OUT1B;
  // distinct ranges anyway)
  unsigned long long* MASKB = (unsigned long long*)(OUT1B + 4194304);  // 512 KB

  prep<<<2304, 256, 0, stream>>>(fc_w, wq, wk, wv, mask, WFC, W3T, MASKB);
  gemm_qkv<<<768, 256, 0, stream>>>(q, k, v, W3T, HEADS);
  attn_kernel<<<1024, 256, 0, stream>>>(HEADS, MASKB, CONCAT);
  gemm_fc64<<<512, 256, 0, stream>>>(CONCAT, WFC, OUT1B, q);
  ln_kernel<<<4096, 256, 0, stream>>>(OUT1B, ln_g, ln_b, out);
}

// Round 18
// 107.260 us; speedup vs baseline: 1.3230x; 1.0374x over previous
//
#include <hip/hip_runtime.h>
#include <hip/hip_bf16.h>

typedef __bf16 bf16x8 __attribute__((ext_vector_type(8)));
typedef __bf16 bf16x4 __attribute__((ext_vector_type(4)));
typedef __bf16 bf16x2 __attribute__((ext_vector_type(2)));
typedef float f32x4 __attribute__((ext_vector_type(4)));
typedef unsigned int u32x2 __attribute__((ext_vector_type(2)));

#define MFMA16(a, b, c) __builtin_amdgcn_mfma_f32_16x16x32_bf16(a, b, c, 0, 0, 0)

static constexpr int M_ = 4096;     // B*S rows

__device__ __forceinline__ void gload_lds16(const void* g, void* l) {
  __builtin_amdgcn_global_load_lds((const __attribute__((address_space(1))) void*)g,
                                   (__attribute__((address_space(3))) void*)l, 16, 0, 0);
}

// single-instruction 2^x (inputs bounded |x|<~12 here; no denorm fixup needed)
__device__ __forceinline__ float exp2_hw(float x) {
  float r;
  asm("v_exp_f32 %0, %1" : "=v"(r) : "v"(x));
  return r;
}

__device__ __forceinline__ bf16x8 cvt8(float4 x, float4 y) {
  bf16x8 o;
  o[0] = (__bf16)x.x; o[1] = (__bf16)x.y; o[2] = (__bf16)x.z; o[3] = (__bf16)x.w;
  o[4] = (__bf16)y.x; o[5] = (__bf16)y.y; o[6] = (__bf16)y.z; o[7] = (__bf16)y.w;
  return o;
}

// swizzled LDS u16 index for 64-col bf16 tiles (128B rows, 8 granules):
// stored granule = logical granule ^ (row & 7)
#define SWZ(rowv, c16) (((rowv) * 64) + (((c16) ^ ((rowv) & 7)) * 8))

// ---------------- fused prep: cvt fc_w, wtrans x3, mask bits ----------------
__global__ __launch_bounds__(256) void prep(const float* __restrict__ fc_w,
                                            const float* __restrict__ wq,
                                            const float* __restrict__ wk,
                                            const float* __restrict__ wv,
                                            const int* __restrict__ mask,
                                            __bf16* __restrict__ WFC,
                                            __bf16* __restrict__ W3T,
                                            unsigned long long* __restrict__ bits) {
  __shared__ float tile[64][65];
  int bx = blockIdx.x;
  const int t = threadIdx.x;

  if (bx < 512) {  // --- fc_w f32->bf16 ---
    int i = bx * 256 + t;
    const float4* p = (const float4*)fc_w + (size_t)i * 2;
    float4 a = p[0], b = p[1];
    *((bf16x8*)WFC + i) = cvt8(a, b);
    return;
  }
  bx -= 512;
  if (bx < 768) {  // --- wtrans x3 (256 blocks per z) ---
    const int z = bx >> 8, rem = bx & 255;
    const float* w = z == 0 ? wq : (z == 1 ? wk : wv);
    const float scale = z == 0 ? 0.125f * 1.4426950408889634f : 1.0f;  // 1/sqrt(DK)*log2e in W_q
    __bf16* o = W3T + (size_t)z * 1048576;
    const int h = rem & 15, d0 = (rem >> 4) * 64;
    const int r = t >> 2, c0 = (t & 3) * 16;
    const float4* s4 = (const float4*)(w + ((size_t)h * 1024 + d0 + r) * 64 + c0);
#pragma unroll
    for (int j = 0; j < 4; ++j) {
      float4 vv = s4[j];
      tile[r][c0 + 4 * j + 0] = vv.x; tile[r][c0 + 4 * j + 1] = vv.y;
      tile[r][c0 + 4 * j + 2] = vv.z; tile[r][c0 + 4 * j + 3] = vv.w;
    }
    __syncthreads();
    __bf16* dst = o + ((size_t)(h * 64 + r)) * 1024 + d0 + c0;
    bf16x8 o0, o1;
#pragma unroll
    for (int j = 0; j < 8; ++j) o0[j] = (__bf16)(tile[c0 + j][r] * scale);
#pragma unroll
    for (int j = 0; j < 8; ++j) o1[j] = (__bf16)(tile[c0 + 8 + j][r] * scale);
    *(bf16x8*)dst = o0;
    *(bf16x8*)(dst + 8) = o1;
    return;
  }
  bx -= 768;
  {  // --- mask -> ballot bits (1024 blocks) ---
    const int wid = bx * 4 + (t >> 6);
    const int lane = t & 63;
#pragma unroll
    for (int i = 0; i < 16; ++i) {
      int widx = wid * 16 + i;                 // (b*16 + kt)*1024 + qrow
      int qrow = widx & 1023;
      int bkt = widx >> 10;
      int b = bkt >> 4, kt = bkt & 15;
      int mval = mask[((size_t)b * 1024 + qrow) * 1024 + kt * 64 + lane];
      unsigned long long bal = __ballot(mval != 0);
      if (lane == 0) bits[widx] = bal;
    }
  }
}

// ---------------- QKV GEMM 128x256, 512 threads (8 waves), fused f32-A cvt --------------
// grid = 384 linear; xcd = L&7, wl = xcd*48 + L>>3; bnp = wl&3, bm = (wl>>2)&31, z = wl>>7.
// Per-wave structure identical to the 128x128 form (acc[4][4], 16 MFMA/iter); barriers per
// output element halve, B-panels reused by 12 bm-blocks per XCD.
__global__ __launch_bounds__(512) void gemm_qkv(const float* __restrict__ q,
                                                const float* __restrict__ k,
                                                const float* __restrict__ v,
                                                const __bf16* __restrict__ Btbase,
                                                __bf16* __restrict__ HEADS) {
  // LDS bytes: A bf16 dbuf [0,8K)+[8K,16K); B dbuf [16K,32K)+[32K,48K). Epilogue overlays.
  __shared__ __bf16 SMEM[24576];
  const int L = blockIdx.x;            // 0..383
  const int wl = (L & 7) * 48 + (L >> 3);
  const int bnp = wl & 3;
  const int rem = wl >> 2;             // 0..95
  const int bm = rem & 31, z = rem >> 5;
  const float* Af = z == 0 ? q : (z == 1 ? k : v);
  const __bf16* Bt = Btbase + (size_t)z * 1048576;
  const int tid = threadIdx.x, lane = tid & 63;
  const int w = tid >> 6;              // 0..7
  const int wr = (w >> 2) * 64;        // row group (2)
  const int wcl = (w & 3) * 64;        // col group within 256 (4)
  const int lr = lane & 15, lh = lane >> 4;
  char* smem = (char*)SMEM;
  const int o0 = tid * 16;             // 512 threads x 16B = 8KB

  // A reg staging: thread covers row tid>>2, f32 cols (tid&3)*8..+8 (2x float4); +32 f32/kt
  const float* gA = Af + (size_t)(bm * 128 + (tid >> 2)) * 1024 + (tid & 3) * 8;
  // B staging: [256 rows][32 bf16] per tile; 2 shots of 8KB; +64B per kt
  const char* apB = (const char*)Bt + ((size_t)(bnp * 256 + (tid >> 2)) * 1024) * 2 +
                    (tid & 3) * 16;

#define BSTAGE(buf)                                           \
  do {                                                        \
    char* db = smem + 16384 + (buf) * 16384;                  \
    gload_lds16(apB, db + o0);                                \
    gload_lds16(apB + 262144, db + 8192 + o0);                \
    apB += 64;                                                \
  } while (0)

  f32x4 acc[4][4];
#pragma unroll
  for (int m = 0; m < 4; ++m)
#pragma unroll
    for (int n = 0; n < 4; ++n) {
      f32x4 zz = {0.f, 0.f, 0.f, 0.f};
      acc[m][n] = zz;
    }

  // prologue: A(0) -> cvt -> LDS; B(0) gload
  {
    float4 a0 = *(const float4*)gA, a1 = *(const float4*)(gA + 4);
    gA += 32;
    *(bf16x8*)(smem + o0) = cvt8(a0, a1);
  }
  BSTAGE(0);
  __syncthreads();

  for (int kt = 0; kt < 32; ++kt) {
    const int cur = kt & 1;
    float4 a0, a1;
    if (kt < 31) {
      a0 = *(const float4*)gA; a1 = *(const float4*)(gA + 4);
      gA += 32;
      BSTAGE(cur ^ 1);
    }
    __builtin_amdgcn_sched_barrier(0);   // loads stay above; compute below
    const int ab = cur * 4096;               // u16 elements
    const int bb = 8192 + cur * 8192;
    bf16x8 af[4];
#pragma unroll
    for (int m = 0; m < 4; ++m)
      af[m] = *(const bf16x8*)&SMEM[ab + (wr + m * 16 + lr) * 32 + lh * 8];
    __builtin_amdgcn_s_setprio(1);
#pragma unroll
    for (int n = 0; n < 4; ++n) {
      bf16x8 bfr = *(const bf16x8*)&SMEM[bb + (wcl + n * 16 + lr) * 32 + lh * 8];
#pragma unroll
      for (int m = 0; m < 4; ++m) acc[m][n] = MFMA16(af[m], bfr, acc[m][n]);
    }
    __builtin_amdgcn_s_setprio(0);
    __builtin_amdgcn_sched_barrier(0);   // cvt+write stays below MFMA
    if (kt < 31) {
      char* dA = smem + (cur ^ 1) * 8192;
      *(bf16x8*)(dA + o0) = cvt8(a0, a1);
    }
    __syncthreads();
  }
#undef BSTAGE

  if (z == 2) {
    // V^T epilogue: 4 head-passes; waves with (w&3)==p write their 64x64 quadrant
    // transposed into SMEM[64 dk][132], then all 512 threads copy coalesced rows.
    const size_t vtbase = 2ull * 4194304;
    const size_t bbh = (size_t)(bm >> 3) * 16 + bnp * 4;
    const int kkbase = (bm & 7) * 128;
#pragma unroll
    for (int p = 0; p < 4; ++p) {
      if ((w & 3) == p) {
#pragma unroll
        for (int m = 0; m < 4; ++m)
#pragma unroll
          for (int n = 0; n < 4; ++n) {
            const int dk = n * 16 + lr;
            const int s = wr + m * 16 + lh * 4;
            bf16x4 pv;
#pragma unroll
            for (int j = 0; j < 4; ++j) pv[j] = (__bf16)acc[m][n][j];
            *(bf16x4*)&SMEM[dk * 132 + s] = pv;
          }
      }
      __syncthreads();
      {
        const int dk = tid >> 3, sc = tid & 7;
        const __bf16* srcp = &SMEM[dk * 132 + sc * 16];
        __bf16* dstp = HEADS + vtbase + ((bbh + p) * 64 + dk) * 1024 + kkbase + sc * 16;
#pragma unroll
        for (int u = 0; u < 4; ++u) *(bf16x4*)(dstp + u * 4) = *(const bf16x4*)(srcp + u * 4);
      }
      __syncthreads();
    }
    return;
  }

  // Q/K epilogue: 4 sub-passes (row-half p, col-half ph); 2 waves write 64x128 into
  // SMEM stride-132, then all 512 threads copy 16-col chunks per head.
#pragma unroll
  for (int p = 0; p < 2; ++p)
#pragma unroll
    for (int ph = 0; ph < 2; ++ph) {
      if ((w >> 2) == p && ((w >> 1) & 1) == ph) {
        const int colbase = (w & 1) * 64;
#pragma unroll
        for (int m = 0; m < 4; ++m)
#pragma unroll
          for (int n = 0; n < 4; ++n)
#pragma unroll
            for (int reg = 0; reg < 4; ++reg)
              SMEM[(m * 16 + lh * 4 + reg) * 132 + colbase + n * 16 + lr] =
                  (__bf16)acc[m][n][reg];
      }
      __syncthreads();
      {
        const int rowl = tid >> 3, c0 = (tid & 7) * 16;
        const int row = bm * 128 + p * 64 + rowl;
        const int b_ = row >> 10, s = row & 1023;
        const int col = bnp * 256 + ph * 128 + c0;
        const int h = col >> 6, dk0 = col & 63;
        __bf16* dst = HEADS + (size_t)z * 4194304 + (((size_t)b_ * 16 + h) * 1024 + s) * 64 + dk0;
        const __bf16* srcp = &SMEM[rowl * 132 + c0];
#pragma unroll
        for (int u = 0; u < 4; ++u) *(bf16x4*)(dst + u * 4) = *(const bf16x4*)(srcp + u * 4);
      }
      __syncthreads();
    }
}

// ---------------- fc GEMM 64x128 tile, XCD-swizzled, double-buffered; bf16 output --------
__global__ __launch_bounds__(256) void gemm_fc64(const __bf16* __restrict__ A,
                                                 const __bf16* __restrict__ Bt,
                                                 __bf16* __restrict__ O,
                                                 const float* __restrict__ resid) {
  // bytes: A0 [0,4K) A1 [4K,8K) B0 [8K,16K) B1 [16K,24K)
  __shared__ __bf16 SMEM[12288];
  const int L = blockIdx.x;
  const int wl = (L & 7) * 64 + (L >> 3);
  const int bn = wl & 7, bm = wl >> 3;   // 8 bn-blocks per bm-panel on same XCD
  const int tid = threadIdx.x, lane = tid & 63;
  const int w = tid >> 6;
  const int wc = w * 32;
  const int lr = lane & 15, lh = lane >> 4;

  const int o0 = tid * 16;
  const int row0 = o0 >> 6, cb = o0 & 63;
  const char* apA = (const char*)A + ((size_t)(bm * 64 + row0) * 1024) * 2 + cb;
  const char* apB0 = (const char*)Bt + ((size_t)(bn * 128 + row0) * 1024) * 2 + cb;
  const char* apB1 = apB0 + 64 * 2048;
  char* smem = (char*)SMEM;

#define FSTAGE(buf)                                         \
  do {                                                      \
    gload_lds16(apA, smem + (buf) * 4096 + o0);             \
    char* dd = smem + 8192 + (buf) * 8192;                  \
    gload_lds16(apB0, dd + o0);                             \
    gload_lds16(apB1, dd + 4096 + o0);                      \
    apA += 64; apB0 += 64; apB1 += 64;                      \
  } while (0)

  f32x4 acc[4][2];
#pragma unroll
  for (int m = 0; m < 4; ++m)
#pragma unroll
    for (int n = 0; n < 2; ++n) {
      f32x4 z = {0.f, 0.f, 0.f, 0.f};
      acc[m][n] = z;
    }

  FSTAGE(0);
  __syncthreads();

  for (int kt = 0; kt < 32; ++kt) {
    const int cur = kt & 1;
    if (kt < 31) FSTAGE(cur ^ 1);
    const int ab = cur * 2048;               // elements
    const int bb = 4096 + cur * 4096;
    bf16x8 af[4], bfr[2];
#pragma unroll
    for (int m = 0; m < 4; ++m) af[m] = *(const bf16x8*)&SMEM[ab + (m * 16 + lr) * 32 + lh * 8];
#pragma unroll
    for (int n = 0; n < 2; ++n)
      bfr[n] = *(const bf16x8*)&SMEM[bb + (wc + n * 16 + lr) * 32 + lh * 8];
    __builtin_amdgcn_s_setprio(1);
#pragma unroll
    for (int m = 0; m < 4; ++m)
#pragma unroll
      for (int n = 0; n < 2; ++n) acc[m][n] = MFMA16(af[m], bfr[n], acc[m][n]);
    __builtin_amdgcn_s_setprio(0);
    __syncthreads();
  }
#undef FSTAGE

#pragma unroll
  for (int m = 0; m < 4; ++m)
#pragma unroll
    for (int n = 0; n < 2; ++n)
#pragma unroll
      for (int reg = 0; reg < 4; ++reg) {
        int row = bm * 64 + m * 16 + lh * 4 + reg;
        int col = bn * 128 + wc + n * 16 + lr;
        size_t idx = (size_t)row * 1024 + col;
        O[idx] = (__bf16)(acc[m][n][reg] + resid[idx]);
      }
}

// ---------------- flash attention: no-max softmax (scores provably bounded) ----------------
__global__ __launch_bounds__(256, 4) void attn_kernel(const __bf16* __restrict__ HEADS,
                                                      const unsigned long long* __restrict__ m64,
                                                      __bf16* __restrict__ concat) {
  const __bf16* QH = HEADS;
  const __bf16* KH = HEADS + (size_t)M_ * 1024;
  const __bf16* VT = HEADS + (size_t)2 * M_ * 1024;   // [bh][64][1024]
  __shared__ __bf16 Ks[2][2][32 * 64];   // [buf][stream]  4KB each
  __shared__ __bf16 Vs[2][2][64 * 32];   // [buf][stream]  4KB each
  __shared__ unsigned Psw[2][4][256];    // [stream][wave] 1KB each

  // XCD-aware remap: 8 (b,h) groups per xcd, 16 q-tiles each
  const int d = blockIdx.x;            // 0..1023
  const int xcd = d & 7, j = d >> 3;   // j 0..127
  const int grp = xcd * 8 + (j >> 4);  // 0..63
  const int qt = j & 15;               // 64 q-rows per block
  const int h = grp & 15, b = grp >> 4;

  const int tid = threadIdx.x, lane = tid & 63, w = tid >> 6;
  const int lr = lane & 15, lh = lane >> 4;
  const size_t headoff = ((size_t)b * 16 + h) * 65536;
  const char* Kbase = (const char*)(KH + headoff);   // [1024 kk][64 dk], 128B rows
  const char* Vbase = (const char*)(VT + headoff);   // [64 dv][1024 kk], 2048B rows

  // staging source offsets (pre-swizzled global; LDS dest linear = tid*16)
  const int krow = tid >> 3, kg = tid & 7;
  const int kgo = krow * 128 + ((kg ^ (krow & 7)) * 16);
  const int vrow = tid >> 2, vg = tid & 3;
  const int vgo = vrow * 2048 + ((vg ^ ((vrow >> 1) & 3)) * 16);
  const int ldsb = tid * 16;

  // incremental staging pointers (advance per staged tile)
  const char* kpA = Kbase + kgo;
  const char* kpB = Kbase + 65536 + kgo;
  const char* vpA = Vbase + vgo;
  const char* vpB = Vbase + 1024 + vgo;

#define STAGE(buf)                                          \
  do {                                                      \
    gload_lds16(kpA, (char*)Ks[buf][0] + ldsb);             \
    gload_lds16(kpB, (char*)Ks[buf][1] + ldsb);             \
    gload_lds16(vpA, (char*)Vs[buf][0] + ldsb);             \
    gload_lds16(vpB, (char*)Vs[buf][1] + ldsb);             \
    kpA += 4096; kpB += 4096; vpA += 64; vpB += 64;         \
  } while (0)

  const int qrow = qt * 64 + w * 16 + lr;   // this lane's q-row
  bf16x8 qa[2];
  {
    const __bf16* qptr = QH + headoff + (size_t)qrow * 64 + lh * 8;
    qa[0] = *(const bf16x8*)qptr;
    qa[1] = *(const bf16x8*)(qptr + 32);
  }
  f32x4 oacc[4];
#pragma unroll
  for (int g = 0; g < 4; ++g) {
    f32x4 z = {0.f, 0.f, 0.f, 0.f};
    oacc[g] = z;
  }
  float lrun = 0.f;   // lane-partial softmax denominator (reduced only at epilogue)

  // mask: u64 word j (=t>>1) covers tiles 2j,2j+1 (32 kk each); stream B at +8 words
  const unsigned long long* m64A = m64 + (size_t)b * 16384 + qrow;
  const unsigned long long* m64B = m64A + 8192;
  unsigned long long pairA = m64A[0], pairB = m64B[0];
  unsigned long long pairAn = 0, pairBn = 0;

  // hoisted LDS read offsets (u16 units)
  const int vcol = (lh ^ ((lr >> 1) & 3)) * 8;           // V/P granule
  const int pread = lr * 32 + vcol;                      // pa b128
  const int pG = (lr >> 1) & 3;                          // P write swizzle key
  int kread[2][2], vread[4];
#pragma unroll
  for (int n = 0; n < 2; ++n)
#pragma unroll
    for (int h2 = 0; h2 < 2; ++h2) kread[n][h2] = SWZ(n * 16 + lr, h2 * 4 + lh);
#pragma unroll
  for (int g = 0; g < 4; ++g) vread[g] = (g * 16 + lr) * 32 + vcol;

  // prologue: stage tile 0
  STAGE(0);
  __syncthreads();

#pragma unroll 2
  for (int t = 0; t < 16; ++t) {
    const int cur = t & 1;
    if ((t & 1) == 0 && t < 14) {           // prefetch mask pair for tiles t+2,t+3
      pairAn = m64A[((t >> 1) + 1) * 1024];
      pairBn = m64B[((t >> 1) + 1) * 1024];
    }
    const unsigned mwA = (t & 1) ? (unsigned)(pairA >> 32) : (unsigned)pairA;
    const unsigned mwB = (t & 1) ? (unsigned)(pairB >> 32) : (unsigned)pairB;
    if (t < 15) STAGE(cur ^ 1);

    // S^T = K Q^T for both streams (8 MFMA, independent)
    f32x4 sA[2], sB[2];
#pragma unroll
    for (int n = 0; n < 2; ++n) {
      f32x4 z = {0.f, 0.f, 0.f, 0.f};
      sA[n] = z; sB[n] = z;
    }
    __builtin_amdgcn_s_setprio(1);
#pragma unroll
    for (int n = 0; n < 2; ++n)
#pragma unroll
      for (int h2 = 0; h2 < 2; ++h2) {
        bf16x8 kbA = *(const bf16x8*)&Ks[cur][0][kread[n][h2]];
        bf16x8 kbB = *(const bf16x8*)&Ks[cur][1][kread[n][h2]];
        sA[n] = MFMA16(kbA, qa[h2], sA[n]);
        sB[n] = MFMA16(kbB, qa[h2], sB[n]);
      }
    __builtin_amdgcn_s_setprio(0);

    // no-max softmax: p = bit ? 2^s : 0 ; accumulate lane-partial l
#pragma unroll
    for (int n = 0; n < 2; ++n)
#pragma unroll
      for (int r = 0; r < 4; ++r) {
        unsigned bit = (mwA >> (n * 16 + lh * 4 + r)) & 1u;
        float p = bit ? exp2_hw(sA[n][r]) : 0.0f;
        sA[n][r] = p;
        lrun += p;
      }
#pragma unroll
    for (int n = 0; n < 2; ++n)
#pragma unroll
      for (int r = 0; r < 4; ++r) {
        unsigned bit = (mwB >> (n * 16 + lh * 4 + r)) & 1u;
        float p = bit ? exp2_hw(sB[n][r]) : 0.0f;
        sB[n][r] = p;
        lrun += p;
      }

    // pack P pairs -> LDS (swizzled), read back A-fragments
#pragma unroll
    for (int n = 0; n < 2; ++n) {
      bf16x2 p0, p1;
      p0[0] = (__bf16)sA[n][0]; p0[1] = (__bf16)sA[n][1];
      p1[0] = (__bf16)sA[n][2]; p1[1] = (__bf16)sA[n][3];
      int G = n * 2 + (lh >> 1);
      int addr = lr * 16 + ((G ^ pG) * 4) + (lh & 1) * 2;
      u32x2 wv;
      wv[0] = __builtin_bit_cast(unsigned, p0);
      wv[1] = __builtin_bit_cast(unsigned, p1);
      *(u32x2*)&Psw[0][w][addr] = wv;
    }
#pragma unroll
    for (int n = 0; n < 2; ++n) {
      bf16x2 p0, p1;
      p0[0] = (__bf16)sB[n][0]; p0[1] = (__bf16)sB[n][1];
      p1[0] = (__bf16)sB[n][2]; p1[1] = (__bf16)sB[n][3];
      int G = n * 2 + (lh >> 1);
      int addr = lr * 16 + ((G ^ pG) * 4) + (lh & 1) * 2;
      u32x2 wv;
      wv[0] = __builtin_bit_cast(unsigned, p0);
      wv[1] = __builtin_bit_cast(unsigned, p1);
      *(u32x2*)&Psw[1][w][addr] = wv;
    }
    bf16x8 paA = *(const bf16x8*)&((const __bf16*)Psw[0][w])[pread];
    bf16x8 paB = *(const bf16x8*)&((const __bf16*)Psw[1][w])[pread];

    // O += P V, both streams into ONE accumulator (same scale: no max shift)
    __builtin_amdgcn_s_setprio(1);
#pragma unroll
    for (int g = 0; g < 4; ++g) {
      bf16x8 vbA = *(const bf16x8*)&Vs[cur][0][vread[g]];
      bf16x8 vbB = *(const bf16x8*)&Vs[cur][1][vread[g]];
      oacc[g] = MFMA16(paA, vbA, oacc[g]);
      oacc[g] = MFMA16(paB, vbB, oacc[g]);
    }
    __builtin_amdgcn_s_setprio(0);
    if (t & 1) { pairA = pairAn; pairB = pairBn; }
    __syncthreads();
  }
#undef STAGE

  // epilogue: reduce l across lh groups (once), normalize, store
  lrun += __shfl_xor(lrun, 16, 64);
  lrun += __shfl_xor(lrun, 32, 64);
  const float linv = 1.0f / (lrun + 1e-30f);
  const int qg0 = qt * 64 + w * 16 + lh * 4;
#pragma unroll
  for (int r = 0; r < 4; ++r) {
    const float ir = __shfl(linv, (lane & 48) | (lh * 4 + r), 64);
#pragma unroll
    for (int g = 0; g < 4; ++g)
      concat[((size_t)b * 1024 + qg0 + r) * 1024 + h * 64 + g * 16 + lr] =
          (__bf16)(oacc[g][r] * ir);
  }
}

// ---------------- LayerNorm (bf16 input) ----------------
__global__ __launch_bounds__(256) void ln_kernel(const __bf16* __restrict__ in,
                                                 const float* __restrict__ gam,
                                                 const float* __restrict__ bet,
                                                 float* __restrict__ out) {
  const int row = blockIdx.x, t = threadIdx.x;
  bf16x4 xv = *((const bf16x4*)(in + (size_t)row * 1024) + t);
  float x0 = (float)xv[0], x1 = (float)xv[1], x2 = (float)xv[2], x3 = (float)xv[3];
  float s = x0 + x1 + x2 + x3;
  float sq = x0 * x0 + x1 * x1 + x2 * x2 + x3 * x3;
#pragma unroll
  for (int off = 1; off < 64; off <<= 1) {
    s += __shfl_xor(s, off, 64);
    sq += __shfl_xor(sq, off, 64);
  }
  __shared__ float red[8];
  const int w = t >> 6, lane = t & 63;
  if (lane == 0) { red[w] = s; red[4 + w] = sq; }
  __syncthreads();
  s = red[0] + red[1] + red[2] + red[3];
  sq = red[4] + red[5] + red[6] + red[7];
  const float mu = s * (1.0f / 1024.0f);
  const float var = sq * (1.0f / 1024.0f) - mu * mu;
  const float rstd = rsqrtf(var + 1e-6f);
  float4 g4 = ((const float4*)gam)[t];
  float4 b4 = ((const float4*)bet)[t];
  float4 o;
  o.x = (x0 - mu) * rstd * g4.x + b4.x;
  o.y = (x1 - mu) * rstd * g4.y + b4.y;
  o.z = (x2 - mu) * rstd * g4.z + b4.z;
  o.w = (x3 - mu) * rstd * g4.w + b4.w;
  ((float4*)(out + (size_t)row * 1024))[t] = o;
}

extern "C" void kernel_launch(void* const* d_in, const int* in_sizes, int n_in,
                              void* d_out, int out_size, void* d_ws, size_t ws_size,
                              hipStream_t stream) {
  (void)in_sizes; (void)n_in; (void)out_size; (void)ws_size;
  const float* q = (const float*)d_in[0];
  const float* k = (const float*)d_in[1];
  const float* v = (const float*)d_in[2];
  const int* mask = (const int*)d_in[3];
  const float* wq = (const float*)d_in[4];
  const float* wk = (const float*)d_in[5];
  const float* wv = (const float*)d_in[6];
  const float* fc_w = (const float*)d_in[7];
  const float* ln_g = (const float*)d_in[8];
  const float* ln_b = (const float*)d_in[9];
  float* out = (float*)d_out;

  // workspace layout (~80 MB; QKVBF region unused)
  __bf16* QKVBF = (__bf16*)d_ws;                       // (unused, kept for layout stability)
  __bf16* W3T   = QKVBF + 3ull * 4194304;              // 3 * 1048576 bf16
  __bf16* WFC   = W3T + 3ull * 1048576;                // 1048576 bf16
  __bf16* HEADS = WFC + 1048576;                       // 3 * 4194304 bf16 (V region = V^T)
  __bf16* CONCAT = HEADS + 3ull * 4194304;             // 4194304 bf16
  __bf16* OUT1B = CONCAT + 4194304;                    // 4194304 bf16 (pre-LN, fused resid)
  unsigned long long* MASKB = (unsigned long long*)(OUT1B + 4194304);  // 512 KB

  prep<<<2304, 256, 0, stream>>>(fc_w, wq, wk, wv, mask, WFC, W3T, MASKB);
  gemm_qkv<<<384, 512, 0, stream>>>(q, k, v, W3T, HEADS);
  attn_kernel<<<1024, 256, 0, stream>>>(HEADS, MASKB, CONCAT);
  gemm_fc64<<<512, 256, 0, stream>>>(CONCAT, WFC, OUT1B, q);
  ln_kernel<<<4096, 256, 0, stream>>>(OUT1B, ln_g, ln_b, out);
}